// Round 9
// baseline (422.874 us; speedup 1.0000x reference)
//
#include <hip/hip_runtime.h>
#include <math.h>

#define N_VOX (96*96*96)        // 884736 voxels per volume
#define NVOL 8                  // 4 pred + 4 target volumes
#define NEL (4*N_VOX)           // 3538944 elements in pred/target
#define PLANE (96*96)           // 9216

// tile geometry for local CCL: full d-span x TW x TH
#define TW 8
#define TH 8
#define TILES_W 12
#define TILES_H 12
#define TILE_VOX (96*TW*TH)     // 6144
#define TILE_WORDS (TILE_VOX/32) // 192

#define NBPLANES 11             // interior tile boundaries per axis
#define BOUND_VOX (2*NBPLANES*PLANE)       // 202752 edges/volume = 792*256
#define FACES_PER_VOL (2*2*NBPLANES*PLANE) // 405504 ints
#define MAXR (144*3072)         // hard max roots/volume (<=3072 per tile)
#define EDGE_CAP (2*NBPLANES*PLANE/2)      // 101376: max segment starts/volume
#define HT_SIZE 512             // per-block LDS dedup entries (4 KB)
#define MAX_PROBES 32

// ---------------------------------------------------------------------------
// atomicMin union-find merge; returns # destroyed self-loops (union events).
// Each root destruction observed exactly once (atomicMin returns old value).
__device__ __forceinline__ int merge_count(int* __restrict__ L, int l1, int l2) {
    int ev = 0;
    while (l1 != l2) {
        if (l1 < l2) { int t = l1; l1 = l2; l2 = t; }   // l1 > l2
        int l3 = atomicMin(&L[l1], l2);
        if (l3 == l1) { ev++; l1 = l2; }
        else l1 = l3;
    }
    return ev;
}

// merge on LDS labels (links only run-start slots)
__device__ __forceinline__ void merge_local(int* lab, int l1, int l2) {
    while (l1 != l2 && l1 != lab[l1]) l1 = lab[l1];
    while (l1 != l2 && l2 != lab[l2]) l2 = lab[l2];
    while (l1 != l2) {
        if (l1 < l2) { int t = l1; l1 = l2; l2 = t; }
        int l3 = atomicMin(&lab[l1], l2);
        l1 = (l3 == l1) ? l2 : l3;
    }
}

// start index of the consecutive-fg d-run containing fg voxel i (d = i%96).
__device__ __forceinline__ int run_start(const unsigned* fm, int i, int d) {
    int rowb = (i - d) >> 5;
    int k = d >> 5, bit = d & 31;
    unsigned below = bit ? (~fm[rowb + k] & ((1u << bit) - 1)) : 0u;
    int z = -1;
    if (below) z = (k << 5) + 31 - __builtin_clz(below);
    else if (k > 0) {
        unsigned n1 = ~fm[rowb + k - 1];
        if (n1) z = ((k - 1) << 5) + 31 - __builtin_clz(n1);
        else if (k > 1) {
            unsigned n0 = ~fm[rowb];
            if (n0) z = 31 - __builtin_clz(n0);
        }
    }
    return (i - d) + z + 1;
}

// ---------------------------------------------------------------------------
// Phase 1: run-based per-tile CCL in LDS. Assigns globally-compact root ids
// (base = atomicAdd(rootcnt[v], nroots)), writes resolved rids into the 4
// interior-adjacent face arrays (-1 = bg), and fuses the focal partial.
// No per-voxel label volume is ever materialized.
__global__ __launch_bounds__(256) void ccl_local(const float* __restrict__ pred,
                                                 const float* __restrict__ targ,
                                                 int* __restrict__ faces,
                                                 int* __restrict__ rootcnt,
                                                 float* __restrict__ acc,
                                                 int vbase) {
    __shared__ int lab[TILE_VOX];            // 24 KB
    __shared__ unsigned fm[TILE_WORDS];      // 768 B fg bit array
    __shared__ float fws[4];
    __shared__ int nroots;
    __shared__ int ridbase;

    int vloc = blockIdx.y;
    int v = vbase + vloc;
    int tile = blockIdx.x;                   // 0..143
    int tw = tile % TILES_W, th = tile / TILES_W;
    int w0 = tw * TW, h0 = th * TH;
    int tbase = h0 * PLANE + w0 * 96;
    int* Fw  = faces + (size_t)vloc * FACES_PER_VOL;   // [b][side][h*96+d]
    int* Fh  = Fw + 2 * NBPLANES * PLANE;              // [b][side][w*96+d]
    if (threadIdx.x == 0) nroots = 0;

    // ---- load: fg bits via ballot; fast focal partial for pred volumes ----
    float fsum = 0.0f;
    for (int it = 0; it < TILE_VOX / 256; it++) {
        int i = it * 256 + threadIdx.x;
        int lh = i / 768;                    // i = lh*768 + lw*96 + d
        int j = tbase + i + lh * 8448;
        bool f;
        if (v < 4) {
            float xv = pred[(size_t)v * N_VOX + j];
            float tv = targ[(size_t)v * N_VOX + j];
            f = xv > 0.0f;                   // sigmoid(x)>0.5 <=> x>0
            float m   = (tv == 1.0f) ? -xv : xv;
            float at  = (tv == 1.0f) ? 0.25f : 0.75f;
            float e   = __expf(-fabsf(m));
            float inv = 1.0f / (1.0f + e);
            float sig = inv * ((m >= 0.0f) ? 1.0f : e);    // sigmoid(m)
            float sp  = fmaxf(m, 0.0f) + __logf(1.0f + e); // softplus(m)
            fsum += at * sig * sig * sp;
        } else {
            f = targ[(size_t)(v - 4) * N_VOX + j] > 0.5f;
        }
        unsigned long long bal = __ballot(f);
        if ((threadIdx.x & 63) == 0) {
            fm[i >> 5]       = (unsigned)bal;
            fm[(i >> 5) + 1] = (unsigned)(bal >> 32);
        }
        lab[i] = i;
    }
    __syncthreads();

    // ---- merge: word-level overlap-segment starts, w then h direction ----
    for (int t = threadIdx.x; t < 336; t += 256) {
        bool wdir = t < 168;
        int tt = wdir ? t : t - 168;
        int lh, lw, k;
        if (wdir) { lh = tt / 21; int rem = tt % 21; lw = rem / 3; k = rem % 3; }
        else      { lh = tt / 24; int rem = tt % 24; lw = rem / 3; k = rem % 3; }
        int wb = (lh * 8 + lw) * 3 + k;
        int nb = wb + (wdir ? 3 : 24);
        unsigned ov = fm[wb] & fm[nb];
        if (!ov) continue;
        unsigned carry = (k > 0) ? ((fm[wb - 1] & fm[nb - 1]) >> 31) : 0u;
        unsigned starts = ov & ~((ov << 1) | carry);
        int base_i = wb << 5;
        int dir = wdir ? 96 : 768;
        while (starts) {
            int b = __builtin_ctz(starts);
            starts &= starts - 1;
            int i = base_i + b;
            int d = (k << 5) + b;
            merge_local(lab, run_start(fm, i, d), run_start(fm, i + dir, d));
        }
    }
    __syncthreads();

    // ---- A1: each ROOT run-start gets a local rank, enc = -2-rank ----
    for (int t = threadIdx.x; t < TILE_WORDS; t += 256) {
        unsigned m = fm[t];
        if (!m) continue;
        unsigned carry = (t % 3) ? (fm[t - 1] >> 31) : 0u;
        unsigned starts = m & ~((m << 1) | carry);
        int base_i = t << 5;
        while (starts) {
            int b = __builtin_ctz(starts); starts &= starts - 1;
            int i = base_i + b;
            if (lab[i] == i) {
                int rank = atomicAdd(&nroots, 1);
                lab[i] = -2 - rank;
            }
        }
    }
    __syncthreads();

    // ---- A2: non-root run-starts copy their root's enc (walk ends at <0) --
    for (int t = threadIdx.x; t < TILE_WORDS; t += 256) {
        unsigned m = fm[t];
        if (!m) continue;
        unsigned carry = (t % 3) ? (fm[t - 1] >> 31) : 0u;
        unsigned starts = m & ~((m << 1) | carry);
        int base_i = t << 5;
        while (starts) {
            int b = __builtin_ctz(starts); starts &= starts - 1;
            int i = base_i + b;
            int p = lab[i];
            if (p >= 0) {                       // non-root (roots are neg now)
                int r = p; p = lab[r];
                while (p >= 0) { r = p; p = lab[r]; }
                lab[i] = p;                     // own slot: single writer
            }
        }
    }
    __syncthreads();

    if (threadIdx.x == 0) ridbase = atomicAdd(&rootcnt[v], nroots);
    __syncthreads();
    int base = ridbase;

    // ---- resolve + store the 4 interior-adjacent faces (int4 groups) ----
    for (int t = threadIdx.x; t < 768; t += 256) {
        int f  = t / 192;
        int g  = t % 192;
        int u  = g / 24;                     // row within face (lh or lw)
        int d4 = (g % 24) * 4;
        int i0; int* dst;
        if (f == 0) {
            if (tw == 0) continue;
            i0  = u * 768 + d4;
            dst = Fw + ((tw - 1) * 2 + 1) * PLANE + (h0 + u) * 96 + d4;
        } else if (f == 1) {
            if (tw == TILES_W - 1) continue;
            i0  = u * 768 + 7 * 96 + d4;
            dst = Fw + (tw * 2) * PLANE + (h0 + u) * 96 + d4;
        } else if (f == 2) {
            if (th == 0) continue;
            i0  = u * 96 + d4;
            dst = Fh + ((th - 1) * 2 + 1) * PLANE + (w0 + u) * 96 + d4;
        } else {
            if (th == TILES_H - 1) continue;
            i0  = 7 * 768 + u * 96 + d4;
            dst = Fh + (th * 2) * PLANE + (w0 + u) * 96 + d4;
        }
        unsigned mw = fm[i0 >> 5];
        int vals[4];
        bool prevf = false;
        for (int q = 0; q < 4; q++) {
            bool fb = (mw >> ((d4 & 31) + q)) & 1;
            if (fb) vals[q] = prevf ? vals[q - 1]
                                    : base - 2 - lab[run_start(fm, i0 + q, d4 + q)];
            else vals[q] = -1;
            prevf = fb;
        }
        *(int4*)dst = make_int4(vals[0], vals[1], vals[2], vals[3]);
    }

    // ---- wave-shuffle reduction: focal partial (pred volumes only) ----
    if (v < 4) {
        for (int off = 32; off; off >>= 1) fsum += __shfl_down(fsum, off, 64);
        int wid = threadIdx.x >> 6;
        if ((threadIdx.x & 63) == 0) fws[wid] = fsum;
        __syncthreads();
        if (threadIdx.x == 0) {
            float ft = fws[0] + fws[1] + fws[2] + fws[3];
            if (ft != 0.0f) atomicAdd(acc, ft);
        }
    }
}

// ---------------------------------------------------------------------------
// Phase 2: pure edge extraction. One thread per boundary edge; coalesced face
// reads; segment-start filter; LDS dedup of rid pairs; wave-aggregated append
// to the per-volume edge list. NO global union-find here. Appends are bounded
// by segment starts <= EDGE_CAP, so no overflow is possible.
__global__ __launch_bounds__(256) void ccl_boundary(const int* __restrict__ faces,
                                                    unsigned long long* __restrict__ edges,
                                                    int* __restrict__ edgecnt,
                                                    int vbase) {
    __shared__ unsigned long long ht[HT_SIZE];
    for (int i = threadIdx.x; i < HT_SIZE; i += 256) ht[i] = ~0ull;
    __syncthreads();

    int tid  = blockIdx.x * 256 + threadIdx.x;   // < BOUND_VOX
    int vloc = blockIdx.y;
    const int* F = faces + (size_t)vloc * FACES_PER_VOL;
    unsigned long long* Ebuf = edges + (size_t)vloc * EDGE_CAP;

    int face = tid / PLANE;                      // 0..21
    int e    = tid % PLANE;
    const int* A;
    const int* B;
    if (face < NBPLANES) {
        A = F + (face * 2) * PLANE;
        B = F + (face * 2 + 1) * PLANE;
    } else {
        const int* Fh = F + 2 * NBPLANES * PLANE;
        int b = face - NBPLANES;
        A = Fh + (b * 2) * PLANE;
        B = Fh + (b * 2 + 1) * PLANE;
    }

    int a = A[e], b2 = B[e];
    bool want = false;
    unsigned long long key = 0;
    if (a >= 0 && b2 >= 0) {
        int d = e % 96;
        bool start = (d == 0) || (A[e - 1] < 0) || (B[e - 1] < 0);
        if (start) {                             // a != b2 (different tiles)
            int rmin = a < b2 ? a : b2;
            int rmax = a < b2 ? b2 : a;
            key = ((unsigned long long)rmin << 32) | (unsigned)rmax;
            unsigned long long hsh = (key ^ (key >> 29)) * 0x9E3779B97F4A7C15ull;
            unsigned slot = (unsigned)(hsh >> 43) & (HT_SIZE - 1);
            for (int pr = 0; pr < MAX_PROBES; pr++) {
                unsigned long long prev = atomicCAS(&ht[slot], ~0ull, key);
                if (prev == ~0ull) { want = true; break; }     // inserted
                if (prev == key)   { break; }                  // duplicate
                slot = (slot + 1) & (HT_SIZE - 1);
                if (pr == MAX_PROBES - 1) want = true;         // full: append anyway
            }
        }
    }

    // wave-aggregated append
    unsigned long long mask = __ballot(want);
    if (want) {
        int lane = threadIdx.x & 63;
        int leader = __ffsll((long long)mask) - 1;
        int base = 0;
        if (lane == leader) base = atomicAdd(&edgecnt[vbase + vloc], (int)__popcll(mask));
        base = __shfl(base, leader, 64);
        int rank = (int)__popcll(mask & ((1ull << lane) - 1));
        Ebuf[base + rank] = key;
    }
}

// ---------------------------------------------------------------------------
// Phase 3: one block per volume. Union-find over the compact edge list on a
// compact UF array (single block -> single XCD, L2-hot, no cross-XCD
// ping-pong). Counts union events -> events[v].
__global__ __launch_bounds__(1024) void ccl_resolve(int* __restrict__ UF,
                                                    const unsigned long long* __restrict__ edges,
                                                    const int* __restrict__ edgecnt,
                                                    const int* __restrict__ rootcnt,
                                                    int* __restrict__ events,
                                                    int vbase) {
    __shared__ int sred[16];
    int vloc = blockIdx.x;
    int v = vbase + vloc;
    int R = rootcnt[v];
    int E = edgecnt[v];
    int* U = UF + (size_t)vloc * MAXR;
    const unsigned long long* Ebuf = edges + (size_t)vloc * EDGE_CAP;

    for (int i = threadIdx.x; i < R; i += 1024) U[i] = i;
    __syncthreads();

    int ev = 0;
    for (int e = threadIdx.x; e < E; e += 1024) {
        unsigned long long k = Ebuf[e];
        int a = (int)(k >> 32), b = (int)(unsigned)k;
        ev += merge_count(U, a, b);
    }
    for (int off = 32; off; off >>= 1) ev += __shfl_down(ev, off, 64);
    int wid = threadIdx.x >> 6;
    if ((threadIdx.x & 63) == 0) sred[wid] = ev;
    __syncthreads();
    if (threadIdx.x == 0) {
        int t = 0;
        for (int w = 0; w < 16; w++) t += sred[w];
        events[v] = t;
    }
}

// ---------------------------------------------------------------------------
// components[v] = rootcnt[v] - events[v]
__global__ void finalize_kernel(const float* __restrict__ acc,
                                const int* __restrict__ rootcnt,
                                const int* __restrict__ events,
                                float* __restrict__ out) {
    float focal = acc[0] / (float)NEL;
    float c[NVOL];
    for (int v = 0; v < NVOL; v++) c[v] = (float)(rootcnt[v] - events[v]);
    float dp0 = 0.5f * (c[0] + c[2]);
    float dp1 = 0.5f * (c[1] + c[3]);
    float dt0 = 0.5f * (c[4] + c[6]);
    float dt1 = 0.5f * (c[5] + c[7]);
    float topo = 0.5f * (fabsf(dp0 - dt0) + fabsf(dp1 - dt1));
    out[0] = focal + 0.1f * topo;
}

// ---------------------------------------------------------------------------
extern "C" void kernel_launch(void* const* d_in, const int* in_sizes, int n_in,
                              void* d_out, int out_size, void* d_ws, size_t ws_size,
                              hipStream_t stream) {
    const float* pred = (const float*)d_in[0];
    const float* targ = (const float*)d_in[1];
    float* out = (float*)d_out;

    // header (512 B): [0] float acc; [64..] int rootcnt[8]; [128..] int
    // events[8]; [192..] int edgecnt[8]. Then per-pass arrays:
    // UF[vp*MAXR] ints, faces[vp*FACES_PER_VOL] ints, edges[vp*EDGE_CAP] u64
    float* acc     = (float*)d_ws;
    int*   rootcnt = (int*)((char*)d_ws + 64);
    int*   events  = (int*)((char*)d_ws + 128);
    int*   edgecnt = (int*)((char*)d_ws + 192);
    int*   body    = (int*)((char*)d_ws + 512);

    size_t per_vol = (size_t)MAXR + FACES_PER_VOL + 2 * EDGE_CAP;   // ints
    size_t avail_ints = (ws_size > 512) ? (ws_size - 512) / 4 : 0;
    int vols_per_pass = (int)(avail_ints / per_vol);
    if (vols_per_pass > NVOL) vols_per_pass = NVOL;
    if (vols_per_pass < 1) vols_per_pass = 1;

    int* UF    = body;
    int* faces = UF + (size_t)vols_per_pass * MAXR;
    unsigned long long* edges =
        (unsigned long long*)(faces + (size_t)vols_per_pass * FACES_PER_VOL);

    hipMemsetAsync(d_ws, 0, 512, stream);

    for (int vbase = 0; vbase < NVOL; vbase += vols_per_pass) {
        int nv = NVOL - vbase;
        if (nv > vols_per_pass) nv = vols_per_pass;
        dim3 tgrid(TILES_W * TILES_H, nv);
        ccl_local<<<tgrid, dim3(256), 0, stream>>>(pred, targ, faces,
                                                   rootcnt, acc, vbase);
        dim3 bgrid(BOUND_VOX / 256, nv);
        ccl_boundary<<<bgrid, dim3(256), 0, stream>>>(faces, edges, edgecnt, vbase);
        ccl_resolve<<<dim3(nv), dim3(1024), 0, stream>>>(UF, edges, edgecnt,
                                                         rootcnt, events, vbase);
    }

    finalize_kernel<<<1, 1, 0, stream>>>(acc, rootcnt, events, out);
}